// Round 2
// baseline (184.592 us; speedup 1.0000x reference)
//
#include <hip/hip_runtime.h>
#include <hip/hip_fp16.h>

#define N_NODES 50000
#define N_EDGES 800000
#define FDIM 64
#define N_GRAPHS 500
#define OUTF 10
#define SENT N_NODES
#define ROWCAP 64                       // fixed CSR row capacity; Poisson(16), P(deg>64)~1e-18
#define EV4 (N_EDGES / 4)               // 200000 int4 edge quads
#define FB ((EV4 + 255) / 256)          // 782 scan blocks
#define SEGB ((N_NODES + 256) / 256)    // 196 seg-start blocks

typedef _Float16 f16x8 __attribute__((ext_vector_type(8)));
typedef float f32x4 __attribute__((ext_vector_type(4)));

struct __align__(8) H4 { __half2 a, b; };

__device__ __forceinline__ float rl(float v, int l) {
    return __int_as_float(__builtin_amdgcn_readlane(__float_as_int(v), l));
}

// ---------------- single-scan CSR build + seg starts + W->f16 swizzle ----------------
// Affinity-free single pass: int4-vectorized dst/src reads (was 8x redundant scan;
// atomics resolve at the device coherence point regardless of XCD, so affinity
// bought nothing). Tail blocks: seg starts + W1/W2 -> f16 B-fragment layout
// Wh[kk*4+g][c][j] = W[kk*32+g*8+j][c]  (k-mapping matches the A-frag build below).
__global__ __launch_bounds__(256) void fill_seg(
    const int* __restrict__ src, const int* __restrict__ dst,
    int* __restrict__ deg, int* __restrict__ csr,
    const int* __restrict__ batch, int* __restrict__ start,
    const float* __restrict__ W1, const float* __restrict__ W2,
    __half* __restrict__ Wh1, __half* __restrict__ Wh2) {
    int bid = blockIdx.x, tid = threadIdx.x;
    if (bid < FB) {
        int t = bid * 256 + tid;
        if (t < EV4) {
            int4 d4 = ((const int4*)dst)[t];
            int4 s4 = ((const int4*)src)[t];
            int dd[4] = { d4.x, d4.y, d4.z, d4.w };
            int sv[4] = { s4.x, s4.y, s4.z, s4.w };
            #pragma unroll
            for (int j = 0; j < 4; ++j) {
                int pos = atomicAdd(&deg[dd[j]], 1);
                if (pos < ROWCAP) csr[dd[j] * ROWCAP + pos] = sv[j];
            }
        }
    } else if (bid < FB + SEGB) {
        int i = (bid - FB) * 256 + tid;
        if (i > N_NODES) return;
        int b  = (i < N_NODES) ? batch[i] : N_GRAPHS;
        int bp = (i == 0) ? -1 : batch[i - 1];
        for (int g = bp + 1; g <= b; ++g) start[g] = i;
    } else {
        int wb = bid - (FB + SEGB);                 // 0: W1, 1: W2
        const float* Ws = wb ? W2 : W1;
        __half*      Wo = wb ? Wh2 : Wh1;
        int o0 = tid * 16;
        #pragma unroll
        for (int i = 0; i < 16; ++i) {
            int o = o0 + i;                          // o = gk*512 + c*8 + j
            int j = o & 7, c = (o >> 3) & 63, gk = o >> 9;
            int k = (gk >> 2) * 32 + (gk & 3) * 8 + j;
            Wo[o] = __float2half_rn(Ws[k * FDIM + c]);
        }
    }
}

// ---------------- dinv + prescale x -> fp16, + zero sentinel rows ----------------
__global__ __launch_bounds__(256) void prescale(
    const int* __restrict__ deg, const float* __restrict__ x,
    float* __restrict__ dinv, __half* __restrict__ hsx, __half* __restrict__ hs1) {
    if (blockIdx.x == 0 && threadIdx.x < 2 * FDIM) {
        __half z = __float2half(0.f);
        if (threadIdx.x < FDIM) hsx[(size_t)N_NODES * FDIM + threadIdx.x] = z;
        else                    hs1[(size_t)N_NODES * FDIM + threadIdx.x - FDIM] = z;
    }
    int gid = blockIdx.x * 256 + threadIdx.x;   // float4 index; grid*256 == N_NODES*16 exact
    int n = gid >> 4;
    float dn = rsqrtf((float)deg[n] + 1.0f);    // +1 self-loop
    if ((gid & 15) == 0) dinv[n] = dn;
    float4 vv = ((const float4*)x)[gid];
    H4 o;
    o.a = __floats2half2_rn(vv.x * dn, vv.y * dn);
    o.b = __floats2half2_rn(vv.z * dn, vv.w * dn);
    ((H4*)hsx)[gid] = o;
}

// ---------------- fused GCN layer: gather (4 nodes/wave) + MFMA transform ----------------
// Gather unchanged (dual fp16 chains, csr index double-buffer). Transform replaced:
// per-wave LDS layout swap (ds_write_b64 + 2x ds_read_b128, wave-private -> no
// __syncthreads) feeds 8x mfma_f32_16x16x32_f16 (A rows 0-3 = nodes, rows 4-15
// duplicate; C: col=lane&15, row=(lane>>4)*4+reg, m89-verified). Replaces the
// 64-iter readlane loop (~580 VALU instrs -> ~40 MFMA cycles). W read as
// pre-swizzled f16 B-frags from global (8KB, L1-resident).
template <bool SCALE_OUT, bool POOL>
__global__ __launch_bounds__(256) void gcn_fused(
    const int* __restrict__ deg, const int* __restrict__ csr,
    const float* __restrict__ dinv, const __half* __restrict__ hs,
    const __half* __restrict__ Wh, const float* __restrict__ bias,
    __half* __restrict__ out, const int* __restrict__ batch,
    float* __restrict__ pooled) {
    __shared__ __align__(16) __half A_lds[4][4][FDIM];   // [wave][node][feat], 2KB
    int tid = threadIdx.x;
    int lane = tid & 63;
    int w = tid >> 6;
    int L = lane & 15, q = lane >> 4;
    int nodeBase = (blockIdx.x * 4 + w) * 4;             // grid = 3125 exact
    int myN = nodeBase + q;

    float dn = dinv[myN];
    int d = min(deg[myN], ROWCAP);
    int row = myN << 6;
    int dpad = (d + 7) & ~7;

    H4 sv = *(const H4*)(hs + (size_t)myN * FDIM + 4 * L);  // self term
    __half2 z2 = __floats2half2_rn(0.f, 0.f);
    __half2 c0a = sv.a, c0b = sv.b;
    __half2 c1a = z2,   c1b = z2;

    int4 sA = *(const int4*)(csr + row);
    int4 sB = *(const int4*)(csr + row + 4);
    for (int base = 0; base < dpad; base += 8) {
        int nxt = min(base + 8, 56);
        int4 nA = *(const int4*)(csr + row + nxt);
        int4 nB = *(const int4*)(csr + row + nxt + 4);
        int ss[8] = { sA.x, sA.y, sA.z, sA.w, sB.x, sB.y, sB.z, sB.w };
        #pragma unroll
        for (int j = 0; j < 8; ++j) {
            int e = base + j;
            int s = (e < d) ? ss[j] : SENT;
            H4 hv = *(const H4*)(hs + (size_t)s * FDIM + 4 * L);
            if (j & 1) { c1a = __hadd2(c1a, hv.a); c1b = __hadd2(c1b, hv.b); }
            else       { c0a = __hadd2(c0a, hv.a); c0b = __hadd2(c0b, hv.b); }
        }
        sA = nA; sB = nB;
    }
    float2 t0a = __half22float2(c0a), t1a = __half22float2(c1a);
    float2 t0b = __half22float2(c0b), t1b = __half22float2(c1b);
    float4 acc = make_float4((t0a.x + t1a.x) * dn, (t0a.y + t1a.y) * dn,
                             (t0b.x + t1b.x) * dn, (t0b.y + t1b.y) * dn);

    // ---- layout swap: (node q, feats 4L..4L+3) -> A-frags via wave-private LDS ----
    H4 pk;
    pk.a = __floats2half2_rn(acc.x, acc.y);
    pk.b = __floats2half2_rn(acc.z, acc.w);
    *(H4*)&A_lds[w][q][4 * L] = pk;
    asm volatile("s_waitcnt lgkmcnt(0)" ::: "memory");
    __builtin_amdgcn_sched_barrier(0);
    // lane holds A[row=lane&15][k = kk*32 + q*8 + j]; rows 4-15 duplicate node (row&3)
    f16x8 a0 = *(const f16x8*)&A_lds[w][lane & 3][q * 8];
    f16x8 a1 = *(const f16x8*)&A_lds[w][lane & 3][32 + q * 8];

    // ---- 8x MFMA: C[ct] over 4 col-tiles, K=64 in two kk steps; C seeded with bias ----
    const f16x8* WB = (const f16x8*)Wh;       // [kk*4+g][c] f16x8, c = ct*16+L
    int cb = q * 64 + L;
    float b0 = bias[L], b1 = bias[16 + L], b2 = bias[32 + L], b3 = bias[48 + L];
    f32x4 C0 = {b0, b0, b0, b0}, C1 = {b1, b1, b1, b1};
    f32x4 C2 = {b2, b2, b2, b2}, C3 = {b3, b3, b3, b3};
    {
        f16x8 B0 = WB[cb], B1 = WB[cb + 16], B2 = WB[cb + 32], B3 = WB[cb + 48];
        C0 = __builtin_amdgcn_mfma_f32_16x16x32_f16(a0, B0, C0, 0, 0, 0);
        C1 = __builtin_amdgcn_mfma_f32_16x16x32_f16(a0, B1, C1, 0, 0, 0);
        C2 = __builtin_amdgcn_mfma_f32_16x16x32_f16(a0, B2, C2, 0, 0, 0);
        C3 = __builtin_amdgcn_mfma_f32_16x16x32_f16(a0, B3, C3, 0, 0, 0);
    }
    {
        f16x8 B0 = WB[cb + 256], B1 = WB[cb + 272], B2 = WB[cb + 288], B3 = WB[cb + 304];
        C0 = __builtin_amdgcn_mfma_f32_16x16x32_f16(a1, B0, C0, 0, 0, 0);
        C1 = __builtin_amdgcn_mfma_f32_16x16x32_f16(a1, B1, C1, 0, 0, 0);
        C2 = __builtin_amdgcn_mfma_f32_16x16x32_f16(a1, B2, C2, 0, 0, 0);
        C3 = __builtin_amdgcn_mfma_f32_16x16x32_f16(a1, B3, C3, 0, 0, 0);
    }

    // ---- epilogue on lanes 0-15: C[ct][r] = node nodeBase+r, feat ct*16+L ----
    if (lane < 16) {
        if (POOL) {
            int g0 = batch[nodeBase], g3 = batch[nodeBase + 3];
            if (g0 == g3) {
                float s0 = fmaxf(C0[0],0.f)+fmaxf(C0[1],0.f)+fmaxf(C0[2],0.f)+fmaxf(C0[3],0.f);
                float s1 = fmaxf(C1[0],0.f)+fmaxf(C1[1],0.f)+fmaxf(C1[2],0.f)+fmaxf(C1[3],0.f);
                float s2 = fmaxf(C2[0],0.f)+fmaxf(C2[1],0.f)+fmaxf(C2[2],0.f)+fmaxf(C2[3],0.f);
                float s3 = fmaxf(C3[0],0.f)+fmaxf(C3[1],0.f)+fmaxf(C3[2],0.f)+fmaxf(C3[3],0.f);
                atomicAdd(&pooled[g0 * FDIM +      L], s0);
                atomicAdd(&pooled[g0 * FDIM + 16 + L], s1);
                atomicAdd(&pooled[g0 * FDIM + 32 + L], s2);
                atomicAdd(&pooled[g0 * FDIM + 48 + L], s3);
            } else {
                int g1 = batch[nodeBase + 1], g2 = batch[nodeBase + 2];
                atomicAdd(&pooled[g0 * FDIM +      L], fmaxf(C0[0], 0.f));
                atomicAdd(&pooled[g1 * FDIM +      L], fmaxf(C0[1], 0.f));
                atomicAdd(&pooled[g2 * FDIM +      L], fmaxf(C0[2], 0.f));
                atomicAdd(&pooled[g3 * FDIM +      L], fmaxf(C0[3], 0.f));
                atomicAdd(&pooled[g0 * FDIM + 16 + L], fmaxf(C1[0], 0.f));
                atomicAdd(&pooled[g1 * FDIM + 16 + L], fmaxf(C1[1], 0.f));
                atomicAdd(&pooled[g2 * FDIM + 16 + L], fmaxf(C1[2], 0.f));
                atomicAdd(&pooled[g3 * FDIM + 16 + L], fmaxf(C1[3], 0.f));
                atomicAdd(&pooled[g0 * FDIM + 32 + L], fmaxf(C2[0], 0.f));
                atomicAdd(&pooled[g1 * FDIM + 32 + L], fmaxf(C2[1], 0.f));
                atomicAdd(&pooled[g2 * FDIM + 32 + L], fmaxf(C2[2], 0.f));
                atomicAdd(&pooled[g3 * FDIM + 32 + L], fmaxf(C2[3], 0.f));
                atomicAdd(&pooled[g0 * FDIM + 48 + L], fmaxf(C3[0], 0.f));
                atomicAdd(&pooled[g1 * FDIM + 48 + L], fmaxf(C3[1], 0.f));
                atomicAdd(&pooled[g2 * FDIM + 48 + L], fmaxf(C3[2], 0.f));
                atomicAdd(&pooled[g3 * FDIM + 48 + L], fmaxf(C3[3], 0.f));
            }
        } else {
            float d0 = 1.f, d1 = 1.f, d2 = 1.f, d3 = 1.f;
            if (SCALE_OUT) { d0 = rl(dn, 0); d1 = rl(dn, 16); d2 = rl(dn, 32); d3 = rl(dn, 48); }
            size_t r0 = (size_t)(nodeBase + 0) * FDIM, r1 = (size_t)(nodeBase + 1) * FDIM;
            size_t r2 = (size_t)(nodeBase + 2) * FDIM, r3 = (size_t)(nodeBase + 3) * FDIM;
            out[r0 +      L] = __float2half_rn(fmaxf(C0[0], 0.f) * d0);
            out[r1 +      L] = __float2half_rn(fmaxf(C0[1], 0.f) * d1);
            out[r2 +      L] = __float2half_rn(fmaxf(C0[2], 0.f) * d2);
            out[r3 +      L] = __float2half_rn(fmaxf(C0[3], 0.f) * d3);
            out[r0 + 16 + L] = __float2half_rn(fmaxf(C1[0], 0.f) * d0);
            out[r1 + 16 + L] = __float2half_rn(fmaxf(C1[1], 0.f) * d1);
            out[r2 + 16 + L] = __float2half_rn(fmaxf(C1[2], 0.f) * d2);
            out[r3 + 16 + L] = __float2half_rn(fmaxf(C1[3], 0.f) * d3);
            out[r0 + 32 + L] = __float2half_rn(fmaxf(C2[0], 0.f) * d0);
            out[r1 + 32 + L] = __float2half_rn(fmaxf(C2[1], 0.f) * d1);
            out[r2 + 32 + L] = __float2half_rn(fmaxf(C2[2], 0.f) * d2);
            out[r3 + 32 + L] = __float2half_rn(fmaxf(C2[3], 0.f) * d3);
            out[r0 + 48 + L] = __float2half_rn(fmaxf(C3[0], 0.f) * d0);
            out[r1 + 48 + L] = __float2half_rn(fmaxf(C3[1], 0.f) * d1);
            out[r2 + 48 + L] = __float2half_rn(fmaxf(C3[2], 0.f) * d2);
            out[r3 + 48 + L] = __float2half_rn(fmaxf(C3[3], 0.f) * d3);
        }
    }
}

// ---------------- tiny head: mean + linear + log_softmax from pooled sums ----------------
__global__ __launch_bounds__(256) void head(
    const float* __restrict__ pooled, const int* __restrict__ start,
    const float* __restrict__ Wc, const float* __restrict__ bc,
    float* __restrict__ out) {
    int tid = threadIdx.x;
    int lane = tid & 63;
    int g = blockIdx.x * 4 + (tid >> 6);
    int cnt = start[g + 1] - start[g];
    float c = (float)(cnt > 1 ? cnt : 1);
    float pm = pooled[g * FDIM + lane] / c;

    int j = (lane < OUTF) ? lane : 0;
    float a = bc[j];
    #pragma unroll
    for (int k = 0; k < 64; ++k) a = fmaf(rl(pm, k), Wc[k * OUTF + j], a);

    float m = -1e30f;
    #pragma unroll
    for (int i = 0; i < OUTF; ++i) m = fmaxf(m, rl(a, i));
    float s = 0.f;
    #pragma unroll
    for (int i = 0; i < OUTF; ++i) s += __expf(rl(a, i) - m);
    float lse = m + __logf(s);
    if (lane < OUTF) out[g * OUTF + lane] = a - lse;
}

extern "C" void kernel_launch(void* const* d_in, const int* in_sizes, int n_in,
                              void* d_out, int out_size, void* d_ws, size_t ws_size,
                              hipStream_t stream) {
    const float* x     = (const float*)d_in[0];
    const int*   ei    = (const int*)d_in[1];
    const int*   batch = (const int*)d_in[2];
    const float* W1    = (const float*)d_in[3];
    const float* b1    = (const float*)d_in[4];
    const float* W2    = (const float*)d_in[5];
    const float* b2    = (const float*)d_in[6];
    const float* Wc    = (const float*)d_in[7];
    const float* bc    = (const float*)d_in[8];
    float* out = (float*)d_out;

    const int* src = ei;
    const int* dst = ei + N_EDGES;

    // workspace layout (int units); csr base 16B-aligned; Wh after hs1 (16B-aligned)
    int*    ws     = (int*)d_ws;
    int*    deg    = ws;                                  // 50000 (memset to 0)
    float*  pooled = (float*)(deg + N_NODES);             // 500*64 (memset to 0)
    float*  dinv   = pooled + N_GRAPHS * FDIM;            // 50000
    int*    start  = (int*)(dinv + N_NODES);              // 504
    int*    csr    = start + N_GRAPHS + 4;                // 50000*64 = 3.2M ints
    __half* hsx    = (__half*)(csr + N_NODES * ROWCAP);   // (N_NODES+1)*64 halves
    __half* hs1    = hsx + (size_t)(N_NODES + 1) * FDIM;
    __half* Wh1    = hs1 + (size_t)(N_NODES + 1) * FDIM;  // 4096 halves
    __half* Wh2    = Wh1 + FDIM * FDIM;                   // 4096 halves

    hipMemsetAsync(deg, 0, (N_NODES + N_GRAPHS * FDIM) * sizeof(int), stream);

    fill_seg <<<FB + SEGB + 2, 256, 0, stream>>>(src, dst, deg, csr, batch, start,
                                                 W1, W2, Wh1, Wh2);
    prescale <<<(N_NODES * 16) / 256, 256, 0, stream>>>(deg, x, dinv, hsx, hs1);

    const int gcnGrid = N_NODES / 16;  // 3125 exact
    gcn_fused<true , false><<<gcnGrid, 256, 0, stream>>>(deg, csr, dinv, hsx, Wh1, b1, hs1, nullptr, nullptr);
    gcn_fused<false, true ><<<gcnGrid, 256, 0, stream>>>(deg, csr, dinv, hs1, Wh2, b2, nullptr, batch, pooled);

    head<<<N_GRAPHS / 4, 256, 0, stream>>>(pooled, start, Wc, bc, out);
}

// Round 3
// 174.506 us; speedup vs baseline: 1.0578x; 1.0578x over previous
//
#include <hip/hip_runtime.h>
#include <hip/hip_fp16.h>

#define N_NODES 50000
#define N_EDGES 800000
#define FDIM 64
#define N_GRAPHS 500
#define OUTF 10
#define SENT N_NODES
#define ROWCAP 64                       // fixed CSR row capacity; Poisson(16), P(deg>64)~1e-18
#define SCANB (N_EDGES / 256)           // 3125 scan blocks, one edge per thread (exact)
#define SEGB ((N_NODES + 256) / 256)    // 196 seg-start blocks

typedef _Float16 f16x8 __attribute__((ext_vector_type(8)));
typedef float f32x4 __attribute__((ext_vector_type(4)));

struct __align__(8) H4 { __half2 a, b; };

__device__ __forceinline__ float rl(float v, int l) {
    return __int_as_float(__builtin_amdgcn_readlane(__float_as_int(v), l));
}

// ---------------- CSR build (1 edge/thread, max TLP) + seg starts + W->f16 swizzle ----------------
// Round-2 lesson: the scan is latency-bound on atomic round-trips, so TLP is king.
// 800K threads x (1 atomic + 1 scatter store) instead of 200K threads x 4 chains
// (that was 30% occupancy, 60us). Write-allocate floor: 800K scattered 64B lines
// ~ 45MB -> ~10us; atomics overlap across threads.
__global__ __launch_bounds__(256) void fill_seg(
    const int* __restrict__ src, const int* __restrict__ dst,
    int* __restrict__ deg, int* __restrict__ csr,
    const int* __restrict__ batch, int* __restrict__ start,
    const float* __restrict__ W1, const float* __restrict__ W2,
    __half* __restrict__ Wh1, __half* __restrict__ Wh2) {
    int bid = blockIdx.x, tid = threadIdx.x;
    if (bid < SCANB) {
        int e = bid * 256 + tid;                 // N_EDGES = 3125*256 exact
        int d = dst[e];
        int s = src[e];
        int pos = atomicAdd(&deg[d], 1);
        if (pos < ROWCAP) csr[d * ROWCAP + pos] = s;
    } else if (bid < SCANB + SEGB) {
        int i = (bid - SCANB) * 256 + tid;
        if (i > N_NODES) return;
        int b  = (i < N_NODES) ? batch[i] : N_GRAPHS;
        int bp = (i == 0) ? -1 : batch[i - 1];
        for (int g = bp + 1; g <= b; ++g) start[g] = i;
    } else {
        int wb = bid - (SCANB + SEGB);           // 0: W1, 1: W2
        const float* Ws = wb ? W2 : W1;
        __half*      Wo = wb ? Wh2 : Wh1;
        int o0 = tid * 16;
        #pragma unroll
        for (int i = 0; i < 16; ++i) {
            int o = o0 + i;                      // o = gk*512 + c*8 + j
            int j = o & 7, c = (o >> 3) & 63, gk = o >> 9;
            int k = (gk >> 2) * 32 + (gk & 3) * 8 + j;
            Wo[o] = __float2half_rn(Ws[k * FDIM + c]);
        }
    }
}

// ---------------- dinv + prescale x -> fp16, + zero sentinel rows ----------------
__global__ __launch_bounds__(256) void prescale(
    const int* __restrict__ deg, const float* __restrict__ x,
    float* __restrict__ dinv, __half* __restrict__ hsx, __half* __restrict__ hs1) {
    if (blockIdx.x == 0 && threadIdx.x < 2 * FDIM) {
        __half z = __float2half(0.f);
        if (threadIdx.x < FDIM) hsx[(size_t)N_NODES * FDIM + threadIdx.x] = z;
        else                    hs1[(size_t)N_NODES * FDIM + threadIdx.x - FDIM] = z;
    }
    int gid = blockIdx.x * 256 + threadIdx.x;   // float4 index; grid*256 == N_NODES*16 exact
    int n = gid >> 4;
    float dn = rsqrtf((float)deg[n] + 1.0f);    // +1 self-loop
    if ((gid & 15) == 0) dinv[n] = dn;
    float4 vv = ((const float4*)x)[gid];
    H4 o;
    o.a = __floats2half2_rn(vv.x * dn, vv.y * dn);
    o.b = __floats2half2_rn(vv.z * dn, vv.w * dn);
    ((H4*)hsx)[gid] = o;
}

// ---------------- fused GCN layer: gather (4 nodes/wave) + MFMA transform ----------------
// Gather: dual fp16 chains, csr index double-buffer. Transform: per-wave LDS
// layout swap (wave-private -> no __syncthreads) feeds 8x mfma_f32_16x16x32_f16
// (A rows 0-3 = nodes, rows 4-15 duplicate; C: col=lane&15, row=(lane>>4)*4+reg).
// W read as pre-swizzled f16 B-frags from global (8KB, L1-resident).
template <bool SCALE_OUT, bool POOL>
__global__ __launch_bounds__(256) void gcn_fused(
    const int* __restrict__ deg, const int* __restrict__ csr,
    const float* __restrict__ dinv, const __half* __restrict__ hs,
    const __half* __restrict__ Wh, const float* __restrict__ bias,
    __half* __restrict__ out, const int* __restrict__ batch,
    float* __restrict__ pooled) {
    __shared__ __align__(16) __half A_lds[4][4][FDIM];   // [wave][node][feat], 2KB
    int tid = threadIdx.x;
    int lane = tid & 63;
    int w = tid >> 6;
    int L = lane & 15, q = lane >> 4;
    int nodeBase = (blockIdx.x * 4 + w) * 4;             // grid = 3125 exact
    int myN = nodeBase + q;

    float dn = dinv[myN];
    int d = min(deg[myN], ROWCAP);
    int row = myN << 6;
    int dpad = (d + 7) & ~7;

    H4 sv = *(const H4*)(hs + (size_t)myN * FDIM + 4 * L);  // self term
    __half2 z2 = __floats2half2_rn(0.f, 0.f);
    __half2 c0a = sv.a, c0b = sv.b;
    __half2 c1a = z2,   c1b = z2;

    int4 sA = *(const int4*)(csr + row);
    int4 sB = *(const int4*)(csr + row + 4);
    for (int base = 0; base < dpad; base += 8) {
        int nxt = min(base + 8, 56);
        int4 nA = *(const int4*)(csr + row + nxt);
        int4 nB = *(const int4*)(csr + row + nxt + 4);
        int ss[8] = { sA.x, sA.y, sA.z, sA.w, sB.x, sB.y, sB.z, sB.w };
        #pragma unroll
        for (int j = 0; j < 8; ++j) {
            int e = base + j;
            int s = (e < d) ? ss[j] : SENT;
            H4 hv = *(const H4*)(hs + (size_t)s * FDIM + 4 * L);
            if (j & 1) { c1a = __hadd2(c1a, hv.a); c1b = __hadd2(c1b, hv.b); }
            else       { c0a = __hadd2(c0a, hv.a); c0b = __hadd2(c0b, hv.b); }
        }
        sA = nA; sB = nB;
    }
    float2 t0a = __half22float2(c0a), t1a = __half22float2(c1a);
    float2 t0b = __half22float2(c0b), t1b = __half22float2(c1b);
    float4 acc = make_float4((t0a.x + t1a.x) * dn, (t0a.y + t1a.y) * dn,
                             (t0b.x + t1b.x) * dn, (t0b.y + t1b.y) * dn);

    // ---- layout swap: (node q, feats 4L..4L+3) -> A-frags via wave-private LDS ----
    H4 pk;
    pk.a = __floats2half2_rn(acc.x, acc.y);
    pk.b = __floats2half2_rn(acc.z, acc.w);
    *(H4*)&A_lds[w][q][4 * L] = pk;
    asm volatile("s_waitcnt lgkmcnt(0)" ::: "memory");
    __builtin_amdgcn_sched_barrier(0);
    // lane holds A[row=lane&15][k = kk*32 + q*8 + j]; rows 4-15 duplicate node (row&3)
    f16x8 a0 = *(const f16x8*)&A_lds[w][lane & 3][q * 8];
    f16x8 a1 = *(const f16x8*)&A_lds[w][lane & 3][32 + q * 8];

    // ---- 8x MFMA: C[ct] over 4 col-tiles, K=64 in two kk steps; C seeded with bias ----
    const f16x8* WB = (const f16x8*)Wh;       // [kk*4+g][c] f16x8, c = ct*16+L
    int cb = q * 64 + L;
    float b0 = bias[L], b1 = bias[16 + L], b2 = bias[32 + L], b3 = bias[48 + L];
    f32x4 C0 = {b0, b0, b0, b0}, C1 = {b1, b1, b1, b1};
    f32x4 C2 = {b2, b2, b2, b2}, C3 = {b3, b3, b3, b3};
    {
        f16x8 B0 = WB[cb], B1 = WB[cb + 16], B2 = WB[cb + 32], B3 = WB[cb + 48];
        C0 = __builtin_amdgcn_mfma_f32_16x16x32_f16(a0, B0, C0, 0, 0, 0);
        C1 = __builtin_amdgcn_mfma_f32_16x16x32_f16(a0, B1, C1, 0, 0, 0);
        C2 = __builtin_amdgcn_mfma_f32_16x16x32_f16(a0, B2, C2, 0, 0, 0);
        C3 = __builtin_amdgcn_mfma_f32_16x16x32_f16(a0, B3, C3, 0, 0, 0);
    }
    {
        f16x8 B0 = WB[cb + 256], B1 = WB[cb + 272], B2 = WB[cb + 288], B3 = WB[cb + 304];
        C0 = __builtin_amdgcn_mfma_f32_16x16x32_f16(a1, B0, C0, 0, 0, 0);
        C1 = __builtin_amdgcn_mfma_f32_16x16x32_f16(a1, B1, C1, 0, 0, 0);
        C2 = __builtin_amdgcn_mfma_f32_16x16x32_f16(a1, B2, C2, 0, 0, 0);
        C3 = __builtin_amdgcn_mfma_f32_16x16x32_f16(a1, B3, C3, 0, 0, 0);
    }

    // ---- epilogue on lanes 0-15: C[ct][r] = node nodeBase+r, feat ct*16+L ----
    if (lane < 16) {
        if (POOL) {
            int g0 = batch[nodeBase], g3 = batch[nodeBase + 3];
            if (g0 == g3) {
                float s0 = fmaxf(C0[0],0.f)+fmaxf(C0[1],0.f)+fmaxf(C0[2],0.f)+fmaxf(C0[3],0.f);
                float s1 = fmaxf(C1[0],0.f)+fmaxf(C1[1],0.f)+fmaxf(C1[2],0.f)+fmaxf(C1[3],0.f);
                float s2 = fmaxf(C2[0],0.f)+fmaxf(C2[1],0.f)+fmaxf(C2[2],0.f)+fmaxf(C2[3],0.f);
                float s3 = fmaxf(C3[0],0.f)+fmaxf(C3[1],0.f)+fmaxf(C3[2],0.f)+fmaxf(C3[3],0.f);
                atomicAdd(&pooled[g0 * FDIM +      L], s0);
                atomicAdd(&pooled[g0 * FDIM + 16 + L], s1);
                atomicAdd(&pooled[g0 * FDIM + 32 + L], s2);
                atomicAdd(&pooled[g0 * FDIM + 48 + L], s3);
            } else {
                int g1 = batch[nodeBase + 1], g2 = batch[nodeBase + 2];
                atomicAdd(&pooled[g0 * FDIM +      L], fmaxf(C0[0], 0.f));
                atomicAdd(&pooled[g1 * FDIM +      L], fmaxf(C0[1], 0.f));
                atomicAdd(&pooled[g2 * FDIM +      L], fmaxf(C0[2], 0.f));
                atomicAdd(&pooled[g3 * FDIM +      L], fmaxf(C0[3], 0.f));
                atomicAdd(&pooled[g0 * FDIM + 16 + L], fmaxf(C1[0], 0.f));
                atomicAdd(&pooled[g1 * FDIM + 16 + L], fmaxf(C1[1], 0.f));
                atomicAdd(&pooled[g2 * FDIM + 16 + L], fmaxf(C1[2], 0.f));
                atomicAdd(&pooled[g3 * FDIM + 16 + L], fmaxf(C1[3], 0.f));
                atomicAdd(&pooled[g0 * FDIM + 32 + L], fmaxf(C2[0], 0.f));
                atomicAdd(&pooled[g1 * FDIM + 32 + L], fmaxf(C2[1], 0.f));
                atomicAdd(&pooled[g2 * FDIM + 32 + L], fmaxf(C2[2], 0.f));
                atomicAdd(&pooled[g3 * FDIM + 32 + L], fmaxf(C2[3], 0.f));
                atomicAdd(&pooled[g0 * FDIM + 48 + L], fmaxf(C3[0], 0.f));
                atomicAdd(&pooled[g1 * FDIM + 48 + L], fmaxf(C3[1], 0.f));
                atomicAdd(&pooled[g2 * FDIM + 48 + L], fmaxf(C3[2], 0.f));
                atomicAdd(&pooled[g3 * FDIM + 48 + L], fmaxf(C3[3], 0.f));
            }
        } else {
            float d0 = 1.f, d1 = 1.f, d2 = 1.f, d3 = 1.f;
            if (SCALE_OUT) { d0 = rl(dn, 0); d1 = rl(dn, 16); d2 = rl(dn, 32); d3 = rl(dn, 48); }
            size_t r0 = (size_t)(nodeBase + 0) * FDIM, r1 = (size_t)(nodeBase + 1) * FDIM;
            size_t r2 = (size_t)(nodeBase + 2) * FDIM, r3 = (size_t)(nodeBase + 3) * FDIM;
            out[r0 +      L] = __float2half_rn(fmaxf(C0[0], 0.f) * d0);
            out[r1 +      L] = __float2half_rn(fmaxf(C0[1], 0.f) * d1);
            out[r2 +      L] = __float2half_rn(fmaxf(C0[2], 0.f) * d2);
            out[r3 +      L] = __float2half_rn(fmaxf(C0[3], 0.f) * d3);
            out[r0 + 16 + L] = __float2half_rn(fmaxf(C1[0], 0.f) * d0);
            out[r1 + 16 + L] = __float2half_rn(fmaxf(C1[1], 0.f) * d1);
            out[r2 + 16 + L] = __float2half_rn(fmaxf(C1[2], 0.f) * d2);
            out[r3 + 16 + L] = __float2half_rn(fmaxf(C1[3], 0.f) * d3);
            out[r0 + 32 + L] = __float2half_rn(fmaxf(C2[0], 0.f) * d0);
            out[r1 + 32 + L] = __float2half_rn(fmaxf(C2[1], 0.f) * d1);
            out[r2 + 32 + L] = __float2half_rn(fmaxf(C2[2], 0.f) * d2);
            out[r3 + 32 + L] = __float2half_rn(fmaxf(C2[3], 0.f) * d3);
            out[r0 + 48 + L] = __float2half_rn(fmaxf(C3[0], 0.f) * d0);
            out[r1 + 48 + L] = __float2half_rn(fmaxf(C3[1], 0.f) * d1);
            out[r2 + 48 + L] = __float2half_rn(fmaxf(C3[2], 0.f) * d2);
            out[r3 + 48 + L] = __float2half_rn(fmaxf(C3[3], 0.f) * d3);
        }
    }
}

// ---------------- tiny head: mean + linear + log_softmax from pooled sums ----------------
__global__ __launch_bounds__(256) void head(
    const float* __restrict__ pooled, const int* __restrict__ start,
    const float* __restrict__ Wc, const float* __restrict__ bc,
    float* __restrict__ out) {
    int tid = threadIdx.x;
    int lane = tid & 63;
    int g = blockIdx.x * 4 + (tid >> 6);
    int cnt = start[g + 1] - start[g];
    float c = (float)(cnt > 1 ? cnt : 1);
    float pm = pooled[g * FDIM + lane] / c;

    int j = (lane < OUTF) ? lane : 0;
    float a = bc[j];
    #pragma unroll
    for (int k = 0; k < 64; ++k) a = fmaf(rl(pm, k), Wc[k * OUTF + j], a);

    float m = -1e30f;
    #pragma unroll
    for (int i = 0; i < OUTF; ++i) m = fmaxf(m, rl(a, i));
    float s = 0.f;
    #pragma unroll
    for (int i = 0; i < OUTF; ++i) s += __expf(rl(a, i) - m);
    float lse = m + __logf(s);
    if (lane < OUTF) out[g * OUTF + lane] = a - lse;
}

extern "C" void kernel_launch(void* const* d_in, const int* in_sizes, int n_in,
                              void* d_out, int out_size, void* d_ws, size_t ws_size,
                              hipStream_t stream) {
    const float* x     = (const float*)d_in[0];
    const int*   ei    = (const int*)d_in[1];
    const int*   batch = (const int*)d_in[2];
    const float* W1    = (const float*)d_in[3];
    const float* b1    = (const float*)d_in[4];
    const float* W2    = (const float*)d_in[5];
    const float* b2    = (const float*)d_in[6];
    const float* Wc    = (const float*)d_in[7];
    const float* bc    = (const float*)d_in[8];
    float* out = (float*)d_out;

    const int* src = ei;
    const int* dst = ei + N_EDGES;

    // workspace layout (int units); csr base 16B-aligned; Wh after hs1 (16B-aligned)
    int*    ws     = (int*)d_ws;
    int*    deg    = ws;                                  // 50000 (memset to 0)
    float*  pooled = (float*)(deg + N_NODES);             // 500*64 (memset to 0)
    float*  dinv   = pooled + N_GRAPHS * FDIM;            // 50000
    int*    start  = (int*)(dinv + N_NODES);              // 504
    int*    csr    = start + N_GRAPHS + 4;                // 50000*64 = 3.2M ints
    __half* hsx    = (__half*)(csr + N_NODES * ROWCAP);   // (N_NODES+1)*64 halves
    __half* hs1    = hsx + (size_t)(N_NODES + 1) * FDIM;
    __half* Wh1    = hs1 + (size_t)(N_NODES + 1) * FDIM;  // 4096 halves
    __half* Wh2    = Wh1 + FDIM * FDIM;                   // 4096 halves

    hipMemsetAsync(deg, 0, (N_NODES + N_GRAPHS * FDIM) * sizeof(int), stream);

    fill_seg <<<SCANB + SEGB + 2, 256, 0, stream>>>(src, dst, deg, csr, batch, start,
                                                    W1, W2, Wh1, Wh2);
    prescale <<<(N_NODES * 16) / 256, 256, 0, stream>>>(deg, x, dinv, hsx, hs1);

    const int gcnGrid = N_NODES / 16;  // 3125 exact
    gcn_fused<true , false><<<gcnGrid, 256, 0, stream>>>(deg, csr, dinv, hsx, Wh1, b1, hs1, nullptr, nullptr);
    gcn_fused<false, true ><<<gcnGrid, 256, 0, stream>>>(deg, csr, dinv, hs1, Wh2, b2, nullptr, batch, pooled);

    head<<<N_GRAPHS / 4, 256, 0, stream>>>(pooled, start, Wc, bc, out);
}

// Round 4
// 170.278 us; speedup vs baseline: 1.0841x; 1.0248x over previous
//
#include <hip/hip_runtime.h>
#include <hip/hip_fp16.h>

#define N_NODES 50000
#define N_EDGES 800000
#define FDIM 64
#define N_GRAPHS 500
#define OUTF 10
#define SENT N_NODES
#define ROWCAP 64                       // fixed CSR row capacity; Poisson(16), P(deg>64)~1e-18
#define EV4 (N_EDGES / 4)               // 200000 int4 edge quads
#define FB4 ((EV4 + 255) / 256)         // 782 blocks per XCD group
#define SCANB (FB4 * 8)                 // 6256 scan blocks (8 affinity groups)
#define SEGB ((N_NODES + 256) / 256)    // 196 seg-start blocks

typedef _Float16 f16x8 __attribute__((ext_vector_type(8)));
typedef float f32x4 __attribute__((ext_vector_type(4)));

struct __align__(8) H4 { __half2 a, b; };

__device__ __forceinline__ float rl(float v, int l) {
    return __int_as_float(__builtin_amdgcn_readlane(__float_as_int(v), l));
}

// ---------------- CSR build: XCD-affinity + max-TLP + seg starts + W->f16 swizzle ----------------
// Round-3 lesson: non-affinity scatter stores produced WRITE_SIZE = 800K x 64B
// (each 4B store -> partial dirty line ping-ponged across 8 non-coherent L2s ->
// partial-line ECC writeback). Affinity grouping ((d>>5)&7 == bid&7) makes every
// csr/deg line single-XCD-owned: stores merge in that XCD's L2, full-line
// writeback once. Round-2 lesson: keep chains/thread <= ~1 for TLP -> one int4
// of dst per thread per group (8x read amplification is L2/L3-served, ~free);
// ~52% of threads exit after one 16B load, matched threads do ~1 atomic chain.
__global__ __launch_bounds__(256) void fill_seg(
    const int* __restrict__ src, const int* __restrict__ dst,
    int* __restrict__ deg, int* __restrict__ csr,
    const int* __restrict__ batch, int* __restrict__ start,
    const float* __restrict__ W1, const float* __restrict__ W2,
    __half* __restrict__ Wh1, __half* __restrict__ Wh2) {
    int bid = blockIdx.x, tid = threadIdx.x;
    if (bid < SCANB) {
        int myx = bid & 7;                       // XCD proxy (dispatch round-robin)
        int t = (bid >> 3) * 256 + tid;
        if (t >= EV4) return;
        int4 d4 = ((const int4*)dst)[t];
        bool m0 = ((d4.x >> 5) & 7) == myx;
        bool m1 = ((d4.y >> 5) & 7) == myx;
        bool m2 = ((d4.z >> 5) & 7) == myx;
        bool m3 = ((d4.w >> 5) & 7) == myx;
        if (!(m0 | m1 | m2 | m3)) return;        // early-out before src load
        int4 s4 = ((const int4*)src)[t];
        if (m0) { int p = atomicAdd(&deg[d4.x], 1); if (p < ROWCAP) csr[d4.x * ROWCAP + p] = s4.x; }
        if (m1) { int p = atomicAdd(&deg[d4.y], 1); if (p < ROWCAP) csr[d4.y * ROWCAP + p] = s4.y; }
        if (m2) { int p = atomicAdd(&deg[d4.z], 1); if (p < ROWCAP) csr[d4.z * ROWCAP + p] = s4.z; }
        if (m3) { int p = atomicAdd(&deg[d4.w], 1); if (p < ROWCAP) csr[d4.w * ROWCAP + p] = s4.w; }
    } else if (bid < SCANB + SEGB) {
        int i = (bid - SCANB) * 256 + tid;
        if (i > N_NODES) return;
        int b  = (i < N_NODES) ? batch[i] : N_GRAPHS;
        int bp = (i == 0) ? -1 : batch[i - 1];
        for (int g = bp + 1; g <= b; ++g) start[g] = i;
    } else {
        int wb = bid - (SCANB + SEGB);           // 0: W1, 1: W2
        const float* Ws = wb ? W2 : W1;
        __half*      Wo = wb ? Wh2 : Wh1;
        int o0 = tid * 16;
        #pragma unroll
        for (int i = 0; i < 16; ++i) {
            int o = o0 + i;                      // o = gk*512 + c*8 + j
            int j = o & 7, c = (o >> 3) & 63, gk = o >> 9;
            int k = (gk >> 2) * 32 + (gk & 3) * 8 + j;
            Wo[o] = __float2half_rn(Ws[k * FDIM + c]);
        }
    }
}

// ---------------- dinv + prescale x -> fp16, + zero sentinel rows ----------------
__global__ __launch_bounds__(256) void prescale(
    const int* __restrict__ deg, const float* __restrict__ x,
    float* __restrict__ dinv, __half* __restrict__ hsx, __half* __restrict__ hs1) {
    if (blockIdx.x == 0 && threadIdx.x < 2 * FDIM) {
        __half z = __float2half(0.f);
        if (threadIdx.x < FDIM) hsx[(size_t)N_NODES * FDIM + threadIdx.x] = z;
        else                    hs1[(size_t)N_NODES * FDIM + threadIdx.x - FDIM] = z;
    }
    int gid = blockIdx.x * 256 + threadIdx.x;   // float4 index; grid*256 == N_NODES*16 exact
    int n = gid >> 4;
    float dn = rsqrtf((float)deg[n] + 1.0f);    // +1 self-loop
    if ((gid & 15) == 0) dinv[n] = dn;
    float4 vv = ((const float4*)x)[gid];
    H4 o;
    o.a = __floats2half2_rn(vv.x * dn, vv.y * dn);
    o.b = __floats2half2_rn(vv.z * dn, vv.w * dn);
    ((H4*)hsx)[gid] = o;
}

// ---------------- fused GCN layer: gather (4 nodes/wave) + MFMA transform ----------------
// Gather: dual fp16 chains, csr index double-buffer. Transform: per-wave LDS
// layout swap (wave-private -> no __syncthreads) feeds 8x mfma_f32_16x16x32_f16
// (A rows 0-3 = nodes, rows 4-15 duplicate; C: col=lane&15, row=(lane>>4)*4+reg).
// W read as pre-swizzled f16 B-frags from global (8KB, L1-resident).
template <bool SCALE_OUT, bool POOL>
__global__ __launch_bounds__(256) void gcn_fused(
    const int* __restrict__ deg, const int* __restrict__ csr,
    const float* __restrict__ dinv, const __half* __restrict__ hs,
    const __half* __restrict__ Wh, const float* __restrict__ bias,
    __half* __restrict__ out, const int* __restrict__ batch,
    float* __restrict__ pooled) {
    __shared__ __align__(16) __half A_lds[4][4][FDIM];   // [wave][node][feat], 2KB
    int tid = threadIdx.x;
    int lane = tid & 63;
    int w = tid >> 6;
    int L = lane & 15, q = lane >> 4;
    int nodeBase = (blockIdx.x * 4 + w) * 4;             // grid = 3125 exact
    int myN = nodeBase + q;

    float dn = dinv[myN];
    int d = min(deg[myN], ROWCAP);
    int row = myN << 6;
    int dpad = (d + 7) & ~7;

    H4 sv = *(const H4*)(hs + (size_t)myN * FDIM + 4 * L);  // self term
    __half2 z2 = __floats2half2_rn(0.f, 0.f);
    __half2 c0a = sv.a, c0b = sv.b;
    __half2 c1a = z2,   c1b = z2;

    int4 sA = *(const int4*)(csr + row);
    int4 sB = *(const int4*)(csr + row + 4);
    for (int base = 0; base < dpad; base += 8) {
        int nxt = min(base + 8, 56);
        int4 nA = *(const int4*)(csr + row + nxt);
        int4 nB = *(const int4*)(csr + row + nxt + 4);
        int ss[8] = { sA.x, sA.y, sA.z, sA.w, sB.x, sB.y, sB.z, sB.w };
        #pragma unroll
        for (int j = 0; j < 8; ++j) {
            int e = base + j;
            int s = (e < d) ? ss[j] : SENT;
            H4 hv = *(const H4*)(hs + (size_t)s * FDIM + 4 * L);
            if (j & 1) { c1a = __hadd2(c1a, hv.a); c1b = __hadd2(c1b, hv.b); }
            else       { c0a = __hadd2(c0a, hv.a); c0b = __hadd2(c0b, hv.b); }
        }
        sA = nA; sB = nB;
    }
    float2 t0a = __half22float2(c0a), t1a = __half22float2(c1a);
    float2 t0b = __half22float2(c0b), t1b = __half22float2(c1b);
    float4 acc = make_float4((t0a.x + t1a.x) * dn, (t0a.y + t1a.y) * dn,
                             (t0b.x + t1b.x) * dn, (t0b.y + t1b.y) * dn);

    // ---- layout swap: (node q, feats 4L..4L+3) -> A-frags via wave-private LDS ----
    H4 pk;
    pk.a = __floats2half2_rn(acc.x, acc.y);
    pk.b = __floats2half2_rn(acc.z, acc.w);
    *(H4*)&A_lds[w][q][4 * L] = pk;
    asm volatile("s_waitcnt lgkmcnt(0)" ::: "memory");
    __builtin_amdgcn_sched_barrier(0);
    // lane holds A[row=lane&15][k = kk*32 + q*8 + j]; rows 4-15 duplicate node (row&3)
    f16x8 a0 = *(const f16x8*)&A_lds[w][lane & 3][q * 8];
    f16x8 a1 = *(const f16x8*)&A_lds[w][lane & 3][32 + q * 8];

    // ---- 8x MFMA: C[ct] over 4 col-tiles, K=64 in two kk steps; C seeded with bias ----
    const f16x8* WB = (const f16x8*)Wh;       // [kk*4+g][c] f16x8, c = ct*16+L
    int cb = q * 64 + L;
    float b0 = bias[L], b1 = bias[16 + L], b2 = bias[32 + L], b3 = bias[48 + L];
    f32x4 C0 = {b0, b0, b0, b0}, C1 = {b1, b1, b1, b1};
    f32x4 C2 = {b2, b2, b2, b2}, C3 = {b3, b3, b3, b3};
    {
        f16x8 B0 = WB[cb], B1 = WB[cb + 16], B2 = WB[cb + 32], B3 = WB[cb + 48];
        C0 = __builtin_amdgcn_mfma_f32_16x16x32_f16(a0, B0, C0, 0, 0, 0);
        C1 = __builtin_amdgcn_mfma_f32_16x16x32_f16(a0, B1, C1, 0, 0, 0);
        C2 = __builtin_amdgcn_mfma_f32_16x16x32_f16(a0, B2, C2, 0, 0, 0);
        C3 = __builtin_amdgcn_mfma_f32_16x16x32_f16(a0, B3, C3, 0, 0, 0);
    }
    {
        f16x8 B0 = WB[cb + 256], B1 = WB[cb + 272], B2 = WB[cb + 288], B3 = WB[cb + 304];
        C0 = __builtin_amdgcn_mfma_f32_16x16x32_f16(a1, B0, C0, 0, 0, 0);
        C1 = __builtin_amdgcn_mfma_f32_16x16x32_f16(a1, B1, C1, 0, 0, 0);
        C2 = __builtin_amdgcn_mfma_f32_16x16x32_f16(a1, B2, C2, 0, 0, 0);
        C3 = __builtin_amdgcn_mfma_f32_16x16x32_f16(a1, B3, C3, 0, 0, 0);
    }

    // ---- epilogue on lanes 0-15: C[ct][r] = node nodeBase+r, feat ct*16+L ----
    if (lane < 16) {
        if (POOL) {
            int g0 = batch[nodeBase], g3 = batch[nodeBase + 3];
            if (g0 == g3) {
                float s0 = fmaxf(C0[0],0.f)+fmaxf(C0[1],0.f)+fmaxf(C0[2],0.f)+fmaxf(C0[3],0.f);
                float s1 = fmaxf(C1[0],0.f)+fmaxf(C1[1],0.f)+fmaxf(C1[2],0.f)+fmaxf(C1[3],0.f);
                float s2 = fmaxf(C2[0],0.f)+fmaxf(C2[1],0.f)+fmaxf(C2[2],0.f)+fmaxf(C2[3],0.f);
                float s3 = fmaxf(C3[0],0.f)+fmaxf(C3[1],0.f)+fmaxf(C3[2],0.f)+fmaxf(C3[3],0.f);
                atomicAdd(&pooled[g0 * FDIM +      L], s0);
                atomicAdd(&pooled[g0 * FDIM + 16 + L], s1);
                atomicAdd(&pooled[g0 * FDIM + 32 + L], s2);
                atomicAdd(&pooled[g0 * FDIM + 48 + L], s3);
            } else {
                int g1 = batch[nodeBase + 1], g2 = batch[nodeBase + 2];
                atomicAdd(&pooled[g0 * FDIM +      L], fmaxf(C0[0], 0.f));
                atomicAdd(&pooled[g1 * FDIM +      L], fmaxf(C0[1], 0.f));
                atomicAdd(&pooled[g2 * FDIM +      L], fmaxf(C0[2], 0.f));
                atomicAdd(&pooled[g3 * FDIM +      L], fmaxf(C0[3], 0.f));
                atomicAdd(&pooled[g0 * FDIM + 16 + L], fmaxf(C1[0], 0.f));
                atomicAdd(&pooled[g1 * FDIM + 16 + L], fmaxf(C1[1], 0.f));
                atomicAdd(&pooled[g2 * FDIM + 16 + L], fmaxf(C1[2], 0.f));
                atomicAdd(&pooled[g3 * FDIM + 16 + L], fmaxf(C1[3], 0.f));
                atomicAdd(&pooled[g0 * FDIM + 32 + L], fmaxf(C2[0], 0.f));
                atomicAdd(&pooled[g1 * FDIM + 32 + L], fmaxf(C2[1], 0.f));
                atomicAdd(&pooled[g2 * FDIM + 32 + L], fmaxf(C2[2], 0.f));
                atomicAdd(&pooled[g3 * FDIM + 32 + L], fmaxf(C2[3], 0.f));
                atomicAdd(&pooled[g0 * FDIM + 48 + L], fmaxf(C3[0], 0.f));
                atomicAdd(&pooled[g1 * FDIM + 48 + L], fmaxf(C3[1], 0.f));
                atomicAdd(&pooled[g2 * FDIM + 48 + L], fmaxf(C3[2], 0.f));
                atomicAdd(&pooled[g3 * FDIM + 48 + L], fmaxf(C3[3], 0.f));
            }
        } else {
            float d0 = 1.f, d1 = 1.f, d2 = 1.f, d3 = 1.f;
            if (SCALE_OUT) { d0 = rl(dn, 0); d1 = rl(dn, 16); d2 = rl(dn, 32); d3 = rl(dn, 48); }
            size_t r0 = (size_t)(nodeBase + 0) * FDIM, r1 = (size_t)(nodeBase + 1) * FDIM;
            size_t r2 = (size_t)(nodeBase + 2) * FDIM, r3 = (size_t)(nodeBase + 3) * FDIM;
            out[r0 +      L] = __float2half_rn(fmaxf(C0[0], 0.f) * d0);
            out[r1 +      L] = __float2half_rn(fmaxf(C0[1], 0.f) * d1);
            out[r2 +      L] = __float2half_rn(fmaxf(C0[2], 0.f) * d2);
            out[r3 +      L] = __float2half_rn(fmaxf(C0[3], 0.f) * d3);
            out[r0 + 16 + L] = __float2half_rn(fmaxf(C1[0], 0.f) * d0);
            out[r1 + 16 + L] = __float2half_rn(fmaxf(C1[1], 0.f) * d1);
            out[r2 + 16 + L] = __float2half_rn(fmaxf(C1[2], 0.f) * d2);
            out[r3 + 16 + L] = __float2half_rn(fmaxf(C1[3], 0.f) * d3);
            out[r0 + 32 + L] = __float2half_rn(fmaxf(C2[0], 0.f) * d0);
            out[r1 + 32 + L] = __float2half_rn(fmaxf(C2[1], 0.f) * d1);
            out[r2 + 32 + L] = __float2half_rn(fmaxf(C2[2], 0.f) * d2);
            out[r3 + 32 + L] = __float2half_rn(fmaxf(C2[3], 0.f) * d3);
            out[r0 + 48 + L] = __float2half_rn(fmaxf(C3[0], 0.f) * d0);
            out[r1 + 48 + L] = __float2half_rn(fmaxf(C3[1], 0.f) * d1);
            out[r2 + 48 + L] = __float2half_rn(fmaxf(C3[2], 0.f) * d2);
            out[r3 + 48 + L] = __float2half_rn(fmaxf(C3[3], 0.f) * d3);
        }
    }
}

// ---------------- tiny head: mean + linear + log_softmax from pooled sums ----------------
__global__ __launch_bounds__(256) void head(
    const float* __restrict__ pooled, const int* __restrict__ start,
    const float* __restrict__ Wc, const float* __restrict__ bc,
    float* __restrict__ out) {
    int tid = threadIdx.x;
    int lane = tid & 63;
    int g = blockIdx.x * 4 + (tid >> 6);
    int cnt = start[g + 1] - start[g];
    float c = (float)(cnt > 1 ? cnt : 1);
    float pm = pooled[g * FDIM + lane] / c;

    int j = (lane < OUTF) ? lane : 0;
    float a = bc[j];
    #pragma unroll
    for (int k = 0; k < 64; ++k) a = fmaf(rl(pm, k), Wc[k * OUTF + j], a);

    float m = -1e30f;
    #pragma unroll
    for (int i = 0; i < OUTF; ++i) m = fmaxf(m, rl(a, i));
    float s = 0.f;
    #pragma unroll
    for (int i = 0; i < OUTF; ++i) s += __expf(rl(a, i) - m);
    float lse = m + __logf(s);
    if (lane < OUTF) out[g * OUTF + lane] = a - lse;
}

extern "C" void kernel_launch(void* const* d_in, const int* in_sizes, int n_in,
                              void* d_out, int out_size, void* d_ws, size_t ws_size,
                              hipStream_t stream) {
    const float* x     = (const float*)d_in[0];
    const int*   ei    = (const int*)d_in[1];
    const int*   batch = (const int*)d_in[2];
    const float* W1    = (const float*)d_in[3];
    const float* b1    = (const float*)d_in[4];
    const float* W2    = (const float*)d_in[5];
    const float* b2    = (const float*)d_in[6];
    const float* Wc    = (const float*)d_in[7];
    const float* bc    = (const float*)d_in[8];
    float* out = (float*)d_out;

    const int* src = ei;
    const int* dst = ei + N_EDGES;

    // workspace layout (int units); csr base 16B-aligned; Wh after hs1 (16B-aligned)
    int*    ws     = (int*)d_ws;
    int*    deg    = ws;                                  // 50000 (memset to 0)
    float*  pooled = (float*)(deg + N_NODES);             // 500*64 (memset to 0)
    float*  dinv   = pooled + N_GRAPHS * FDIM;            // 50000
    int*    start  = (int*)(dinv + N_NODES);              // 504
    int*    csr    = start + N_GRAPHS + 4;                // 50000*64 = 3.2M ints
    __half* hsx    = (__half*)(csr + N_NODES * ROWCAP);   // (N_NODES+1)*64 halves
    __half* hs1    = hsx + (size_t)(N_NODES + 1) * FDIM;
    __half* Wh1    = hs1 + (size_t)(N_NODES + 1) * FDIM;  // 4096 halves
    __half* Wh2    = Wh1 + FDIM * FDIM;                   // 4096 halves

    hipMemsetAsync(deg, 0, (N_NODES + N_GRAPHS * FDIM) * sizeof(int), stream);

    fill_seg <<<SCANB + SEGB + 2, 256, 0, stream>>>(src, dst, deg, csr, batch, start,
                                                    W1, W2, Wh1, Wh2);
    prescale <<<(N_NODES * 16) / 256, 256, 0, stream>>>(deg, x, dinv, hsx, hs1);

    const int gcnGrid = N_NODES / 16;  // 3125 exact
    gcn_fused<true , false><<<gcnGrid, 256, 0, stream>>>(deg, csr, dinv, hsx, Wh1, b1, hs1, nullptr, nullptr);
    gcn_fused<false, true ><<<gcnGrid, 256, 0, stream>>>(deg, csr, dinv, hs1, Wh2, b2, nullptr, batch, pooled);

    head<<<N_GRAPHS / 4, 256, 0, stream>>>(pooled, start, Wc, bc, out);
}

// Round 5
// 168.164 us; speedup vs baseline: 1.0977x; 1.0126x over previous
//
#include <hip/hip_runtime.h>
#include <hip/hip_fp16.h>

#define N_NODES 50000
#define N_EDGES 800000
#define FDIM 64
#define N_GRAPHS 500
#define OUTF 10
#define SENT N_NODES
#define ROWCAP 64                       // fixed CSR row capacity; Poisson(16), P(deg>64)~1e-18
#define EV4 (N_EDGES / 4)               // 200000 int4 edge quads
#define FB4 ((EV4 + 255) / 256)         // 782 blocks per XCD group
#define SCANB (FB4 * 8)                 // 6256 scan blocks (8 affinity groups)
#define SEGB ((N_NODES + 256) / 256)    // 196 seg-start blocks

typedef _Float16 f16x8 __attribute__((ext_vector_type(8)));
typedef float f32x4 __attribute__((ext_vector_type(4)));

struct __align__(8)  H4 { __half2 a, b; };
struct __align__(16) H8 { __half2 a, b, c, d; };

__device__ __forceinline__ float rl(float v, int l) {
    return __int_as_float(__builtin_amdgcn_readlane(__float_as_int(v), l));
}

// ---------------- CSR build: XCD-affinity + max-TLP + seg starts + W->f16 swizzle ----------------
// Affinity grouping ((d>>5)&7 == bid&7) keeps every csr/deg line single-XCD-owned:
// stores merge in that XCD's L2, full-line writeback once (R3->R4: 47->~43us).
// One int4 of dst per thread per group; ~52% of threads exit after one 16B load.
__global__ __launch_bounds__(256) void fill_seg(
    const int* __restrict__ src, const int* __restrict__ dst,
    int* __restrict__ deg, int* __restrict__ csr,
    const int* __restrict__ batch, int* __restrict__ start,
    const float* __restrict__ W1, const float* __restrict__ W2,
    __half* __restrict__ Wh1, __half* __restrict__ Wh2) {
    int bid = blockIdx.x, tid = threadIdx.x;
    if (bid < SCANB) {
        int myx = bid & 7;                       // XCD proxy (dispatch round-robin)
        int t = (bid >> 3) * 256 + tid;
        if (t >= EV4) return;
        int4 d4 = ((const int4*)dst)[t];
        bool m0 = ((d4.x >> 5) & 7) == myx;
        bool m1 = ((d4.y >> 5) & 7) == myx;
        bool m2 = ((d4.z >> 5) & 7) == myx;
        bool m3 = ((d4.w >> 5) & 7) == myx;
        if (!(m0 | m1 | m2 | m3)) return;        // early-out before src load
        int4 s4 = ((const int4*)src)[t];
        if (m0) { int p = atomicAdd(&deg[d4.x], 1); if (p < ROWCAP) csr[d4.x * ROWCAP + p] = s4.x; }
        if (m1) { int p = atomicAdd(&deg[d4.y], 1); if (p < ROWCAP) csr[d4.y * ROWCAP + p] = s4.y; }
        if (m2) { int p = atomicAdd(&deg[d4.z], 1); if (p < ROWCAP) csr[d4.z * ROWCAP + p] = s4.z; }
        if (m3) { int p = atomicAdd(&deg[d4.w], 1); if (p < ROWCAP) csr[d4.w * ROWCAP + p] = s4.w; }
    } else if (bid < SCANB + SEGB) {
        int i = (bid - SCANB) * 256 + tid;
        if (i > N_NODES) return;
        int b  = (i < N_NODES) ? batch[i] : N_GRAPHS;
        int bp = (i == 0) ? -1 : batch[i - 1];
        for (int g = bp + 1; g <= b; ++g) start[g] = i;
    } else {
        int wb = bid - (SCANB + SEGB);           // 0: W1, 1: W2
        const float* Ws = wb ? W2 : W1;
        __half*      Wo = wb ? Wh2 : Wh1;
        int o0 = tid * 16;
        #pragma unroll
        for (int i = 0; i < 16; ++i) {
            int o = o0 + i;                      // o = gk*512 + c*8 + j
            int j = o & 7, c = (o >> 3) & 63, gk = o >> 9;
            int k = (gk >> 2) * 32 + (gk & 3) * 8 + j;
            Wo[o] = __float2half_rn(Ws[k * FDIM + c]);
        }
    }
}

// ---------------- dinv + prescale x -> fp16, + zero sentinel rows ----------------
__global__ __launch_bounds__(256) void prescale(
    const int* __restrict__ deg, const float* __restrict__ x,
    float* __restrict__ dinv, __half* __restrict__ hsx, __half* __restrict__ hs1) {
    if (blockIdx.x == 0 && threadIdx.x < 2 * FDIM) {
        __half z = __float2half(0.f);
        if (threadIdx.x < FDIM) hsx[(size_t)N_NODES * FDIM + threadIdx.x] = z;
        else                    hs1[(size_t)N_NODES * FDIM + threadIdx.x - FDIM] = z;
    }
    int gid = blockIdx.x * 256 + threadIdx.x;   // float4 index; grid*256 == N_NODES*16 exact
    int n = gid >> 4;
    float dn = rsqrtf((float)deg[n] + 1.0f);    // +1 self-loop
    if ((gid & 15) == 0) dinv[n] = dn;
    float4 vv = ((const float4*)x)[gid];
    H4 o;
    o.a = __floats2half2_rn(vv.x * dn, vv.y * dn);
    o.b = __floats2half2_rn(vv.z * dn, vv.w * dn);
    ((H4*)hsx)[gid] = o;
}

// ---------------- fused GCN layer: 8 nodes/wave (16B gathers) + MFMA transform ----------------
// R4 lever: gcn is latency-bound (each wave: 2-3 gather batches x L2/L3 latency),
// so halve the wave count at constant per-wave work: 8 lanes/node x 16B (H8 =
// dwordx4) instead of 16 lanes x 8B. 6250 waves/layer (was 12500), same load
// depth (8 in flight), same index double-buffer. A-tile rows 0-7 = 8 real nodes
// (rows 8-15 duplicate; C rows 8-15 ignored). LDS stride 72 -> conflict-free
// write AND read phases. Epilogue on lanes 0-31 (C: col=lane&15,
// row=(lane>>4)*4+reg). Pool fast path: shfl_down(.,16) folds rows 4-7 into
// 0-3 -> 4 atomics per 8 nodes.
template <bool SCALE_OUT, bool POOL>
__global__ __launch_bounds__(256) void gcn_fused(
    const int* __restrict__ deg, const int* __restrict__ csr,
    const float* __restrict__ dinv, const __half* __restrict__ hs,
    const __half* __restrict__ Wh, const float* __restrict__ bias,
    __half* __restrict__ out, const int* __restrict__ batch,
    float* __restrict__ pooled) {
    __shared__ __align__(16) __half A_lds[4][8][72];     // [wave][node][feat], stride 72 kills bank conflicts
    int tid = threadIdx.x;
    int lane = tid & 63;
    int w = tid >> 6;
    int q8 = lane >> 3, L8 = lane & 7;                   // node 0..7, 16B chunk 0..7
    int nodeBase = (blockIdx.x * 4 + w) * 8;             // grid = 1563 (last block partial)
    int myN = nodeBase + q8;
    bool valid = myN < N_NODES;
    int myNc = valid ? myN : SENT;                       // sentinel row = zeros

    float dn = dinv[min(myN, N_NODES - 1)];
    int d = valid ? min(deg[min(myN, N_NODES - 1)], ROWCAP) : 0;
    int row = myNc << 6;                                 // row reads stay in workspace
    int dpad = (d + 7) & ~7;

    H8 sv = *(const H8*)(hs + (size_t)myNc * FDIM + 8 * L8);   // self term
    __half2 z2 = __floats2half2_rn(0.f, 0.f);
    __half2 c0[4] = { sv.a, sv.b, sv.c, sv.d };          // chain 0 seeded with self
    __half2 c1[4] = { z2, z2, z2, z2 };

    int4 sA = *(const int4*)(csr + row);                 // prime index pipeline
    int4 sB = *(const int4*)(csr + row + 4);
    for (int base = 0; base < dpad; base += 8) {
        int nxt = min(base + 8, 56);                     // stays inside this node's row
        int4 nA = *(const int4*)(csr + row + nxt);
        int4 nB = *(const int4*)(csr + row + nxt + 4);
        int ss[8] = { sA.x, sA.y, sA.z, sA.w, sB.x, sB.y, sB.z, sB.w };
        #pragma unroll
        for (int j = 0; j < 8; ++j) {
            int e = base + j;
            int s = (e < d) ? ss[j] : SENT;              // mask pad garbage BEFORE load
            H8 hv = *(const H8*)(hs + (size_t)s * FDIM + 8 * L8);
            if (j & 1) {
                c1[0] = __hadd2(c1[0], hv.a); c1[1] = __hadd2(c1[1], hv.b);
                c1[2] = __hadd2(c1[2], hv.c); c1[3] = __hadd2(c1[3], hv.d);
            } else {
                c0[0] = __hadd2(c0[0], hv.a); c0[1] = __hadd2(c0[1], hv.b);
                c0[2] = __hadd2(c0[2], hv.c); c0[3] = __hadd2(c0[3], hv.d);
            }
        }
        sA = nA; sB = nB;
    }
    // combine chains in fp32, scale by dinv, pack to f16
    __half2 pk2[4];
    #pragma unroll
    for (int k = 0; k < 4; ++k) {
        float2 u = __half22float2(c0[k]);
        float2 v = __half22float2(c1[k]);
        pk2[k] = __floats2half2_rn((u.x + v.x) * dn, (u.y + v.y) * dn);
    }
    H8 pk = { pk2[0], pk2[1], pk2[2], pk2[3] };

    // ---- layout swap via wave-private LDS (no __syncthreads) ----
    *(H8*)&A_lds[w][q8][8 * L8] = pk;
    asm volatile("s_waitcnt lgkmcnt(0)" ::: "memory");
    __builtin_amdgcn_sched_barrier(0);
    int q = (lane >> 4) & 3, L = lane & 15;
    // A[row=lane&15][k = kk*32 + q*8 + j]; physical rows 0-7, rows 8-15 duplicate
    f16x8 a0 = *(const f16x8*)&A_lds[w][lane & 7][q * 8];
    f16x8 a1 = *(const f16x8*)&A_lds[w][lane & 7][32 + q * 8];

    // ---- 8x MFMA: 4 col-tiles, K=64 in two kk steps; C seeded with bias ----
    const f16x8* WB = (const f16x8*)Wh;       // [kk*4+g][c] f16x8, c = ct*16+L
    int cb = q * 64 + L;
    float b0 = bias[L], b1 = bias[16 + L], b2 = bias[32 + L], b3 = bias[48 + L];
    f32x4 C0 = {b0, b0, b0, b0}, C1 = {b1, b1, b1, b1};
    f32x4 C2 = {b2, b2, b2, b2}, C3 = {b3, b3, b3, b3};
    {
        f16x8 B0 = WB[cb], B1 = WB[cb + 16], B2 = WB[cb + 32], B3 = WB[cb + 48];
        C0 = __builtin_amdgcn_mfma_f32_16x16x32_f16(a0, B0, C0, 0, 0, 0);
        C1 = __builtin_amdgcn_mfma_f32_16x16x32_f16(a0, B1, C1, 0, 0, 0);
        C2 = __builtin_amdgcn_mfma_f32_16x16x32_f16(a0, B2, C2, 0, 0, 0);
        C3 = __builtin_amdgcn_mfma_f32_16x16x32_f16(a0, B3, C3, 0, 0, 0);
    }
    {
        f16x8 B0 = WB[cb + 256], B1 = WB[cb + 272], B2 = WB[cb + 288], B3 = WB[cb + 304];
        C0 = __builtin_amdgcn_mfma_f32_16x16x32_f16(a1, B0, C0, 0, 0, 0);
        C1 = __builtin_amdgcn_mfma_f32_16x16x32_f16(a1, B1, C1, 0, 0, 0);
        C2 = __builtin_amdgcn_mfma_f32_16x16x32_f16(a1, B2, C2, 0, 0, 0);
        C3 = __builtin_amdgcn_mfma_f32_16x16x32_f16(a1, B3, C3, 0, 0, 0);
    }

    // ---- epilogue: lane<32 holds rows 0-7 (node = nodeBase + (lane>>4)*4 + reg) ----
    int col = lane & 15;
    int half = (lane >> 4) & 1;
    if (POOL) {
        // per-ct partial over this lane's 4 rows (all lanes compute; 32-63 unused)
        float p0 = fmaxf(C0[0],0.f)+fmaxf(C0[1],0.f)+fmaxf(C0[2],0.f)+fmaxf(C0[3],0.f);
        float p1 = fmaxf(C1[0],0.f)+fmaxf(C1[1],0.f)+fmaxf(C1[2],0.f)+fmaxf(C1[3],0.f);
        float p2 = fmaxf(C2[0],0.f)+fmaxf(C2[1],0.f)+fmaxf(C2[2],0.f)+fmaxf(C2[3],0.f);
        float p3 = fmaxf(C3[0],0.f)+fmaxf(C3[1],0.f)+fmaxf(C3[2],0.f)+fmaxf(C3[3],0.f);
        p0 += __shfl_down(p0, 16); p1 += __shfl_down(p1, 16);
        p2 += __shfl_down(p2, 16); p3 += __shfl_down(p3, 16);
        bool allv = (nodeBase + 7) < N_NODES;
        int g0 = batch[min(nodeBase,     N_NODES - 1)];
        int gL = batch[min(nodeBase + 7, N_NODES - 1)];
        if (allv && g0 == gL) {
            if (lane < 16) {
                atomicAdd(&pooled[g0 * FDIM +      col], p0);
                atomicAdd(&pooled[g0 * FDIM + 16 + col], p1);
                atomicAdd(&pooled[g0 * FDIM + 32 + col], p2);
                atomicAdd(&pooled[g0 * FDIM + 48 + col], p3);
            }
        } else if (lane < 32) {
            #pragma unroll
            for (int r = 0; r < 4; ++r) {
                int node = nodeBase + half * 4 + r;
                if (node < N_NODES) {
                    int g = batch[node];
                    atomicAdd(&pooled[g * FDIM +      col], fmaxf(C0[r], 0.f));
                    atomicAdd(&pooled[g * FDIM + 16 + col], fmaxf(C1[r], 0.f));
                    atomicAdd(&pooled[g * FDIM + 32 + col], fmaxf(C2[r], 0.f));
                    atomicAdd(&pooled[g * FDIM + 48 + col], fmaxf(C3[r], 0.f));
                }
            }
        }
    } else if (lane < 32) {
        #pragma unroll
        for (int r = 0; r < 4; ++r) {
            int nl = half * 4 + r;
            int node = nodeBase + nl;
            if (node < N_NODES) {
                float sc = 1.f;
                if (SCALE_OUT) sc = __shfl(dn, nl * 8);   // dn lives on lanes q8*8
                size_t ro = (size_t)node * FDIM;
                out[ro +      col] = __float2half_rn(fmaxf(C0[r], 0.f) * sc);
                out[ro + 16 + col] = __float2half_rn(fmaxf(C1[r], 0.f) * sc);
                out[ro + 32 + col] = __float2half_rn(fmaxf(C2[r], 0.f) * sc);
                out[ro + 48 + col] = __float2half_rn(fmaxf(C3[r], 0.f) * sc);
            }
        }
    }
}

// ---------------- tiny head: mean + linear + log_softmax from pooled sums ----------------
__global__ __launch_bounds__(256) void head(
    const float* __restrict__ pooled, const int* __restrict__ start,
    const float* __restrict__ Wc, const float* __restrict__ bc,
    float* __restrict__ out) {
    int tid = threadIdx.x;
    int lane = tid & 63;
    int g = blockIdx.x * 4 + (tid >> 6);
    int cnt = start[g + 1] - start[g];
    float c = (float)(cnt > 1 ? cnt : 1);
    float pm = pooled[g * FDIM + lane] / c;

    int j = (lane < OUTF) ? lane : 0;
    float a = bc[j];
    #pragma unroll
    for (int k = 0; k < 64; ++k) a = fmaf(rl(pm, k), Wc[k * OUTF + j], a);

    float m = -1e30f;
    #pragma unroll
    for (int i = 0; i < OUTF; ++i) m = fmaxf(m, rl(a, i));
    float s = 0.f;
    #pragma unroll
    for (int i = 0; i < OUTF; ++i) s += __expf(rl(a, i) - m);
    float lse = m + __logf(s);
    if (lane < OUTF) out[g * OUTF + lane] = a - lse;
}

extern "C" void kernel_launch(void* const* d_in, const int* in_sizes, int n_in,
                              void* d_out, int out_size, void* d_ws, size_t ws_size,
                              hipStream_t stream) {
    const float* x     = (const float*)d_in[0];
    const int*   ei    = (const int*)d_in[1];
    const int*   batch = (const int*)d_in[2];
    const float* W1    = (const float*)d_in[3];
    const float* b1    = (const float*)d_in[4];
    const float* W2    = (const float*)d_in[5];
    const float* b2    = (const float*)d_in[6];
    const float* Wc    = (const float*)d_in[7];
    const float* bc    = (const float*)d_in[8];
    float* out = (float*)d_out;

    const int* src = ei;
    const int* dst = ei + N_EDGES;

    // workspace layout (int units); csr base 16B-aligned; Wh after hs1 (16B-aligned)
    int*    ws     = (int*)d_ws;
    int*    deg    = ws;                                  // 50000 (memset to 0)
    float*  pooled = (float*)(deg + N_NODES);             // 500*64 (memset to 0)
    float*  dinv   = pooled + N_GRAPHS * FDIM;            // 50000
    int*    start  = (int*)(dinv + N_NODES);              // 504
    int*    csr    = start + N_GRAPHS + 4;                // 50000*64 = 3.2M ints
    __half* hsx    = (__half*)(csr + N_NODES * ROWCAP);   // (N_NODES+1)*64 halves
    __half* hs1    = hsx + (size_t)(N_NODES + 1) * FDIM;
    __half* Wh1    = hs1 + (size_t)(N_NODES + 1) * FDIM;  // 4096 halves
    __half* Wh2    = Wh1 + FDIM * FDIM;                   // 4096 halves

    hipMemsetAsync(deg, 0, (N_NODES + N_GRAPHS * FDIM) * sizeof(int), stream);

    fill_seg <<<SCANB + SEGB + 2, 256, 0, stream>>>(src, dst, deg, csr, batch, start,
                                                    W1, W2, Wh1, Wh2);
    prescale <<<(N_NODES * 16) / 256, 256, 0, stream>>>(deg, x, dinv, hsx, hs1);

    const int gcnGrid = (N_NODES + 31) / 32;  // 1563, 8 nodes/wave
    gcn_fused<true , false><<<gcnGrid, 256, 0, stream>>>(deg, csr, dinv, hsx, Wh1, b1, hs1, nullptr, nullptr);
    gcn_fused<false, true ><<<gcnGrid, 256, 0, stream>>>(deg, csr, dinv, hs1, Wh2, b2, nullptr, batch, pooled);

    head<<<N_GRAPHS / 4, 256, 0, stream>>>(pooled, start, Wc, bc, out);
}